// Round 6
// baseline (194.233 us; speedup 1.0000x reference)
//
#include <hip/hip_runtime.h>
#include <math.h>

#define Bsz 128
#define Usz 16
#define Dsz 256
#define Nsz 1024
#define Osz 256
#define BK  64
#define LDT 72   // LDS row stride in u16 (144B, 16B-aligned for b128)

typedef __attribute__((ext_vector_type(2))) unsigned int u32x2;
typedef __attribute__((ext_vector_type(4))) unsigned int u32x4;
typedef __attribute__((ext_vector_type(4))) float f32x4;
typedef __attribute__((ext_vector_type(8))) short bf16x8;

__device__ __forceinline__ unsigned int fbits(float f) {
    union { float f; unsigned int u; } v; v.f = f; return v.u;
}
// pack two f32 -> (bf16(hi)<<16)|bf16(lo) by truncation: 1 v_perm_b32
__device__ __forceinline__ unsigned int pk(float lo, float hi) {
    return __builtin_amdgcn_perm(fbits(hi), fbits(lo), 0x07060302u);
}
__device__ __forceinline__ unsigned short bf16t(float f) {
    return (unsigned short)(fbits(f) >> 16);
}

// Barrier WITHOUT the vmcnt(0) drain __syncthreads() emits. In-flight global
// loads target registers only; barrier needs LDS visibility: lgkmcnt(0).
// Un-clobbered asm (a "memory" clobber makes SIInsertWaitcnts drain vmcnt(0)
// -- v3 lesson), ordered by sched_barrier(0) (rule #18).
__device__ __forceinline__ void sync_nodrain() {
    __builtin_amdgcn_sched_barrier(0);
    asm volatile("s_waitcnt lgkmcnt(0)");
    __builtin_amdgcn_sched_barrier(0);
    __builtin_amdgcn_s_barrier();
    __builtin_amdgcn_sched_barrier(0);
}

// ---------------- lr = softmax_u(X·alr / T) ----------------
__global__ __launch_bounds__(256)
void lr_kernel(const float* __restrict__ X, const float* __restrict__ alr,
               const float* __restrict__ temp, float* __restrict__ lr)
{
    const int b = blockIdx.x;
    const int t = threadIdx.x;
    const int u = t >> 4;
    const int l = t & 15;
    const f32x4* xp = (const f32x4*)(X + ((size_t)b * Usz + u) * Dsz + l * 16);
    const f32x4* ap = (const f32x4*)(alr + (size_t)u * Dsz + l * 16);
    float s = 0.f;
    #pragma unroll
    for (int j = 0; j < 4; j++) {
        const f32x4 xv = xp[j], av = ap[j];
        s += xv[0]*av[0] + xv[1]*av[1] + xv[2]*av[2] + xv[3]*av[3];
    }
    s += __shfl_down(s, 8, 16);
    s += __shfl_down(s, 4, 16);
    s += __shfl_down(s, 2, 16);
    s += __shfl_down(s, 1, 16);
    __shared__ float logits[16];
    if (l == 0) logits[u] = s;
    __syncthreads();
    if (t < 16) {
        const float T = temp[0];
        float m = -1e30f;
        #pragma unroll
        for (int i = 0; i < 16; i++) m = fmaxf(m, logits[i] / T);
        float sum = 0.f;
        #pragma unroll
        for (int i = 0; i < 16; i++) sum += expf(logits[i] / T - m);
        lr[(size_t)b * Usz + t] = expf(logits[t] / T - m) / sum;
    }
}

// ---- state GEMM v6: C = [X | state] · [Win ; sr*W], K=1280 ----
// M-tile 64, N-tile 32, grid 1024 = mt2 x u16 x nt32 -> 4 blocks/CU.
// BOTH operands LDS-staged with dense dwordx4 global loads:
//   A: 4 dwordx4/thread (64B contig), pack->bf16, 4 ds_write_b64.
//   B: 2 dwordx4/thread (k=kB and kB+32; v5 BUG: only half the 64x32 B tile
//      was staged -- k 32..63 read uninitialized LDS), transpose-store [n][k].
// Load->LDS-write distance = 1 full step (E/O raw reg double-buffers).
// 1 nodrain barrier/step. sr folded into B-pack. Wave = 32m x 16n.
__global__ __launch_bounds__(256)
void state_gemm(const float* __restrict__ X, const float* __restrict__ state,
                const float* __restrict__ W, const float* __restrict__ Win,
                const float* __restrict__ bias, const float* __restrict__ sr,
                const float* __restrict__ lr, float* __restrict__ out0)
{
    const int id = blockIdx.x;          // 1024 = mt2 x u16 x nt32 (nt inner)
    const int nt = id & 31;
    const int u  = (id >> 5) & 15;
    const int mt = id >> 9;

    const int tid  = threadIdx.x;
    const int wave = tid >> 6, lane = tid & 63;
    const int l16  = lane & 15, kgl = lane >> 4;
    const int wm = wave & 1, wn = wave >> 1;

    __shared__ unsigned short As[2][64 * LDT];   // 18.0 KB
    __shared__ unsigned short Bs[2][32 * LDT];   //  9.0 KB

    const float sru = sr[u];

    // A staging: thread -> (row rA = tid>>2 in 0..63, kc = (tid&3)*16)
    const int rA = tid >> 2;
    const int cA = (tid & 3) * 16;
    // B staging: thread -> (k = kB and kB+32, kB = tid>>3 in 0..31;
    //                       n = nB..nB+3, nB = (tid&7)*4)
    const int kB = tid >> 3;
    const int nB = (tid & 7) * 4;
    const int col0 = nt * 32;

    f32x4 rAE[4], rAO[4];     // A raw double-buffer
    f32x4 rBE[2], rBO[2];     // B raw double-buffer (two k-halves)

    auto ldA = [&](int s, f32x4 (&ra)[4]) {
        const int k0 = s * BK;
        const float* base = (k0 < Dsz)
            ? X     + (((size_t)(mt * 64 + rA) * Usz + u) * Dsz) + k0 + cA
            : state + (((size_t)(mt * 64 + rA) * Usz + u) * Nsz) + (k0 - Dsz) + cA;
        #pragma unroll
        for (int j = 0; j < 4; j++) ra[j] = *(const f32x4*)(base + 4 * j);
    };
    auto ldB = [&](int s, f32x4 (&rb)[2]) {
        const int k0 = s * BK;
        const float* base = (k0 < Dsz)
            ? Win + (size_t)u * Dsz * Nsz + (size_t)(k0 + kB) * Nsz + col0 + nB
            : W   + (size_t)u * Nsz * Nsz + (size_t)(k0 - Dsz + kB) * Nsz + col0 + nB;
        rb[0] = *(const f32x4*)base;
        rb[1] = *(const f32x4*)(base + (size_t)32 * Nsz);
    };
    auto wrA = [&](int p, f32x4 (&ra)[4]) {
        #pragma unroll
        for (int j = 0; j < 4; j++) {
            u32x2 w; w[0] = pk(ra[j][0], ra[j][1]); w[1] = pk(ra[j][2], ra[j][3]);
            *(u32x2*)&As[p][rA * LDT + cA + 4 * j] = w;
        }
    };
    auto wrB = [&](int p, f32x4 (&rb)[2], float sc) {
        #pragma unroll
        for (int h = 0; h < 2; h++)
            #pragma unroll
            for (int j = 0; j < 4; j++)
                Bs[p][(nB + j) * LDT + kB + 32 * h] = bf16t(rb[h][j] * sc);
    };

    f32x4 acc[2] = {};
    auto comp = [&](int p) {
        #pragma unroll
        for (int kk = 0; kk < 2; kk++) {
            const bf16x8 bf = *(const bf16x8*)&Bs[p][(wn * 16 + l16) * LDT + kk * 32 + kgl * 8];
            #pragma unroll
            for (int mi = 0; mi < 2; mi++) {
                const bf16x8 af = *(const bf16x8*)&As[p][(wm * 32 + mi * 16 + l16) * LDT + kk * 32 + kgl * 8];
                acc[mi] = __builtin_amdgcn_mfma_f32_16x16x32_bf16(af, bf, acc[mi], 0, 0, 0);
            }
        }
    };
    auto scB = [&](int s) -> float { return (s * BK < Dsz) ? 1.f : sru; };

    // prologue: raw(0)->E, raw(1)->O, stage step0 into buf0
    ldA(0, rAE); ldB(0, rBE);
    ldA(1, rAO); ldB(1, rBO);
    wrA(0, rAE); wrB(0, rBE, scB(0));
    sync_nodrain();

    for (int s2 = 0; s2 < 10; s2++) {
        const int s = 2 * s2;
        // even: consume buf0(step s); stage step s+1; prefetch raw s+2
        if (s + 2 < 20) { ldA(s + 2, rAE); ldB(s + 2, rBE); }
        wrA(1, rAO); wrB(1, rBO, scB(s + 1));
        comp(0);
        sync_nodrain();
        // odd: consume buf1(step s+1); stage step s+2; prefetch raw s+3
        if (s + 3 < 20) { ldA(s + 3, rAO); ldB(s + 3, rBO); }
        if (s + 2 < 20) { wrA(0, rAE); wrB(0, rBE, scB(s + 2)); }
        comp(1);
        sync_nodrain();
    }

    // C/D layout: col=lane&15, row=(lane>>4)*4+reg (HW-verified)
    const int gcol = nt * 32 + wn * 16 + l16;
    const float bi = bias[u * Nsz + gcol];
    #pragma unroll
    for (int mi = 0; mi < 2; mi++) {
        #pragma unroll
        for (int rg = 0; rg < 4; rg++) {
            const int grow = mt * 64 + wm * 32 + mi * 16 + kgl * 4 + rg;
            const size_t idx = ((size_t)grow * Usz + u) * Nsz + gcol;
            const float th = tanhf(acc[mi][rg] + bi);
            const float lv = lr[grow * Usz + u];
            out0[idx] = (1.f - lv) * state[idx] + lv * th;
        }
    }
}

// ---- out GEMM v6: ns(128xK=1024) · Wout(Kx256), same structure, split-K ----
// grid = ks4 x mt2 x u16 x ot8 = 1024; each block M64 x N32, nsteps K-steps.
__global__ __launch_bounds__(256)
void out_gemm(const float* __restrict__ ns, const float* __restrict__ Wout,
              float* __restrict__ dst, int nsteps, int partial)
{
    const int id = blockIdx.x;
    const int ot = id & 7;
    const int u  = (id >> 3) & 15;
    const int mt = (id >> 7) & 1;
    const int ks = id >> 8;
    const int kbase = ks * nsteps * BK;

    const int tid  = threadIdx.x;
    const int wave = tid >> 6, lane = tid & 63;
    const int l16  = lane & 15, kgl = lane >> 4;
    const int wm = wave & 1, wn = wave >> 1;

    __shared__ unsigned short As[2][64 * LDT];
    __shared__ unsigned short Bs[2][32 * LDT];

    const int rA = tid >> 2;
    const int cA = (tid & 3) * 16;
    const int kB = tid >> 3;
    const int nB = (tid & 7) * 4;
    const int col0 = ot * 32;

    f32x4 rAE[4], rAO[4];
    f32x4 rBE[2], rBO[2];

    auto ldA = [&](int s, f32x4 (&ra)[4]) {
        const float* base = ns + (((size_t)(mt * 64 + rA) * Usz + u) * Nsz) + kbase + s * BK + cA;
        #pragma unroll
        for (int j = 0; j < 4; j++) ra[j] = *(const f32x4*)(base + 4 * j);
    };
    auto ldB = [&](int s, f32x4 (&rb)[2]) {
        const float* base = Wout + (size_t)u * Nsz * Osz
                          + (size_t)(kbase + s * BK + kB) * Osz + col0 + nB;
        rb[0] = *(const f32x4*)base;
        rb[1] = *(const f32x4*)(base + (size_t)32 * Osz);
    };
    auto wrA = [&](int p, f32x4 (&ra)[4]) {
        #pragma unroll
        for (int j = 0; j < 4; j++) {
            u32x2 w; w[0] = pk(ra[j][0], ra[j][1]); w[1] = pk(ra[j][2], ra[j][3]);
            *(u32x2*)&As[p][rA * LDT + cA + 4 * j] = w;
        }
    };
    auto wrB = [&](int p, f32x4 (&rb)[2]) {
        #pragma unroll
        for (int h = 0; h < 2; h++)
            #pragma unroll
            for (int j = 0; j < 4; j++)
                Bs[p][(nB + j) * LDT + kB + 32 * h] = bf16t(rb[h][j]);
    };

    f32x4 acc[2] = {};
    auto comp = [&](int p) {
        #pragma unroll
        for (int kk = 0; kk < 2; kk++) {
            const bf16x8 bf = *(const bf16x8*)&Bs[p][(wn * 16 + l16) * LDT + kk * 32 + kgl * 8];
            #pragma unroll
            for (int mi = 0; mi < 2; mi++) {
                const bf16x8 af = *(const bf16x8*)&As[p][(wm * 32 + mi * 16 + l16) * LDT + kk * 32 + kgl * 8];
                acc[mi] = __builtin_amdgcn_mfma_f32_16x16x32_bf16(af, bf, acc[mi], 0, 0, 0);
            }
        }
    };

    ldA(0, rAE); ldB(0, rBE);
    ldA(1, rAO); ldB(1, rBO);
    wrA(0, rAE); wrB(0, rBE);
    sync_nodrain();

    for (int s2 = 0; s2 < nsteps / 2; s2++) {
        const int s = 2 * s2;
        if (s + 2 < nsteps) { ldA(s + 2, rAE); ldB(s + 2, rBE); }
        wrA(1, rAO); wrB(1, rBO);
        comp(0);
        sync_nodrain();
        if (s + 3 < nsteps) { ldA(s + 3, rAO); ldB(s + 3, rBO); }
        if (s + 2 < nsteps) { wrA(0, rAE); wrB(0, rBE); }
        comp(1);
        sync_nodrain();
    }

    const int gcol = ot * 32 + wn * 16 + l16;
    #pragma unroll
    for (int mi = 0; mi < 2; mi++) {
        #pragma unroll
        for (int rg = 0; rg < 4; rg++) {
            const int grow = mt * 64 + wm * 32 + mi * 16 + kgl * 4 + rg;
            if (partial)
                dst[(((size_t)ks * 16 + u) * 128 + grow) * 256 + gcol] = acc[mi][rg];
            else
                dst[((size_t)grow * Usz + u) * Osz + gcol] = acc[mi][rg];
        }
    }
}

// ---- sum 4 out-partials -> out1. 512 blocks x 256 thr ----
__global__ __launch_bounds__(256)
void out_reduce(const float* __restrict__ part, float* __restrict__ out1)
{
    const size_t i = (size_t)blockIdx.x * 256 + threadIdx.x;   // 0..131071
    const size_t base = i * 4;                 // flat [m][u][o]
    const int m = (int)(base >> 12);
    const int u = (int)((base >> 8) & 15);
    const int o = (int)(base & 255);

    const size_t pb = ((size_t)u * 128 + m) * 256 + o;
    const size_t slab = (size_t)16 * 128 * 256;
    f32x4 s = *(const f32x4*)(part + pb);
    s += *(const f32x4*)(part + pb + slab);
    s += *(const f32x4*)(part + pb + 2 * slab);
    s += *(const f32x4*)(part + pb + 3 * slab);
    *(f32x4*)(out1 + base) = s;
}

extern "C" void kernel_launch(void* const* d_in, const int* in_sizes, int n_in,
                              void* d_out, int out_size, void* d_ws, size_t ws_size,
                              hipStream_t stream)
{
    (void)in_sizes; (void)n_in; (void)out_size;
    const float* X     = (const float*)d_in[0];
    const float* state = (const float*)d_in[1];
    const float* W     = (const float*)d_in[2];
    const float* Win   = (const float*)d_in[3];
    const float* bias  = (const float*)d_in[4];
    const float* Wout  = (const float*)d_in[5];
    const float* sr    = (const float*)d_in[6];
    const float* alr   = (const float*)d_in[7];
    const float* temp  = (const float*)d_in[8];

    float* out0 = (float*)d_out;                      // (B,U,N)
    float* out1 = out0 + (size_t)Bsz * Usz * Nsz;     // (B,U,O)
    float* lr   = (float*)d_ws;                       // 8 KB

    const size_t p_off   = 8192;
    const size_t p_bytes = (size_t)4 * 16 * 128 * 256 * 4;   // 8 MiB

    lr_kernel<<<Bsz, 256, 0, stream>>>(X, alr, temp, lr);
    state_gemm<<<1024, 256, 0, stream>>>(X, state, W, Win, bias, sr, lr, out0);

    if (ws_size >= p_off + p_bytes) {
        float* part = (float*)((char*)d_ws + p_off);
        out_gemm<<<1024, 256, 0, stream>>>(out0, Wout, part, 4, 1);   // ks4
        out_reduce<<<512, 256, 0, stream>>>(part, out1);
    } else {
        out_gemm<<<256, 256, 0, stream>>>(out0, Wout, out1, 16, 0);   // ks1
    }
}